// Round 1
// baseline (1302.897 us; speedup 1.0000x reference)
//
#include <hip/hip_runtime.h>
#include <math.h>

// BalancingLoss: mean_i( w_i * (-log_softmax(logits)[i, t_i]) )
//   w_i = class_weight_table[text_keys[i], targets[i]]
// B=8192 rows, C=32000 cols, fp32. HBM-read-bound on logits (1.05 GB).
//
// Kernel 1: one block per row, online softmax (single pass over the row),
//           float4 coalesced loads, per-row result -> d_ws[row].
// Kernel 2: single block reduces 8192 partials to the scalar mean -> d_out.
// (d_out/d_ws are poisoned 0xAA before every launch, so no atomics into
//  uninitialized memory; every d_ws slot we read is written first.)

__global__ __launch_bounds__(256) void row_loss_kernel(
    const float* __restrict__ logits,
    const int*   __restrict__ targets,
    const int*   __restrict__ text_keys,
    const float* __restrict__ wtab,
    float*       __restrict__ row_out,
    int C)
{
    const int row = blockIdx.x;
    const float* rowp = logits + (size_t)row * (size_t)C;
    const int tid = threadIdx.x;

    float m = -INFINITY;   // running max
    float s = 0.0f;        // running sum of exp(x - m)

    // vectorized main body: 16 B/lane, consecutive lanes -> consecutive float4
    const int nvec = C >> 2;
    const float4* rowv = (const float4*)rowp;
    for (int i = tid; i < nvec; i += 256) {
        float4 x = rowv[i];
        float mx = fmaxf(fmaxf(x.x, x.y), fmaxf(x.z, x.w));
        float mn = fmaxf(m, mx);
        s = s * __expf(m - mn)
          + __expf(x.x - mn) + __expf(x.y - mn)
          + __expf(x.z - mn) + __expf(x.w - mn);
        m = mn;
    }
    // scalar remainder (C % 4), none for C=32000 but keep it general
    for (int i = (nvec << 2) + tid; i < C; i += 256) {
        float x = rowp[i];
        float mn = fmaxf(m, x);
        s = s * __expf(m - mn) + __expf(x - mn);
        m = mn;
    }

    // wave(64)-level (m,s) merge via shuffles
    #pragma unroll
    for (int off = 32; off > 0; off >>= 1) {
        float mo = __shfl_down(m, off, 64);
        float so = __shfl_down(s, off, 64);
        float mn = fmaxf(m, mo);
        s = s * __expf(m - mn) + so * __expf(mo - mn);
        m = mn;
    }

    // cross-wave merge via LDS (4 waves / block)
    __shared__ float sm[4], ss[4];
    const int wave = tid >> 6;
    const int lane = tid & 63;
    if (lane == 0) { sm[wave] = m; ss[wave] = s; }
    __syncthreads();
    if (tid == 0) {
        float M = sm[0], S = ss[0];
        #pragma unroll
        for (int w = 1; w < 4; ++w) {
            float mo = sm[w], so = ss[w];
            float mn = fmaxf(M, mo);
            S = S * __expf(M - mn) + so * __expf(mo - mn);
            M = mn;
        }
        const int t = targets[row];
        const float lt = rowp[t];
        const float ce = __logf(S) + M - lt;           // -log_softmax at target
        const float w = wtab[(size_t)text_keys[row] * (size_t)C + t];
        row_out[row] = ce * w;
    }
}

__global__ __launch_bounds__(256) void reduce_mean_kernel(
    const float* __restrict__ row_out, float* __restrict__ out, int B)
{
    const int tid = threadIdx.x;
    float acc = 0.0f;
    for (int i = tid; i < B; i += 256) acc += row_out[i];
    #pragma unroll
    for (int off = 32; off > 0; off >>= 1)
        acc += __shfl_down(acc, off, 64);
    __shared__ float sa[4];
    const int wave = tid >> 6;
    const int lane = tid & 63;
    if (lane == 0) sa[wave] = acc;
    __syncthreads();
    if (tid == 0) {
        out[0] = (sa[0] + sa[1] + sa[2] + sa[3]) / (float)B;
    }
}

extern "C" void kernel_launch(void* const* d_in, const int* in_sizes, int n_in,
                              void* d_out, int out_size, void* d_ws, size_t ws_size,
                              hipStream_t stream) {
    const float* logits    = (const float*)d_in[0];
    const int*   targets   = (const int*)d_in[1];
    const int*   text_keys = (const int*)d_in[2];
    const float* wtab      = (const float*)d_in[3];
    float* out    = (float*)d_out;
    float* row_ws = (float*)d_ws;   // B floats of scratch (32 KB)

    const int B = in_sizes[1];           // 8192
    const int C = in_sizes[0] / B;       // 32000

    row_loss_kernel<<<B, 256, 0, stream>>>(logits, targets, text_keys, wtab,
                                           row_ws, C);
    reduce_mean_kernel<<<1, 256, 0, stream>>>(row_ws, out, B);
}